// Round 7
// baseline (105.440 us; speedup 1.0000x reference)
//
#include <hip/hip_runtime.h>

#define NBLK 32
#define TPB  256
#define PSTRIDE64 64   // rounds 0/1 publish stride in u64s
#define R3BASE 4096    // round-3 region base (u64 index)
#define R3STRIDE 320   // round-3 per-block stride in u64s (holds 258)

__device__ __forceinline__ float relu_(float x) { return fmaxf(x, 0.f); }

// R10 = R7 champion (fused {data,seq} u64 protocol, 98.97 us) with the 4th
// grid round eliminated: round 3 publishes 42 group logits + 216 final-combo
// logits (all 36 (a4,a5) variants — per-lane values computed with op-order
// identical to the old final eval, reduced across lanes via padded-LDS
// transpose + butterfly-order tree => bit-identical h). Blocks 1..31 publish
// and exit; only block 0 polls (batched issue-then-check), resolves a4,a5
// from the 42 (unchanged math), selects the winning combo's 6 logits, fans
// in across bb=0..31 in the old order, writes out.
// Fixes R4's two killers: no 216-shfl butterfly, no loop-carried h36 regs.
// Poison 0xAAAAAAAA never matches seq floats 1..3 -> no init kernel.

__launch_bounds__(TPB, 1)
__global__ void actor_kernel(
    const float* __restrict__ inp,
    const float* __restrict__ conv_w, const float* __restrict__ conv_b,
    const float* __restrict__ w0, const float* __restrict__ b0,
    const float* __restrict__ w1, const float* __restrict__ b1,
    const float* __restrict__ w2, const float* __restrict__ b2,
    const float* __restrict__ w3, const float* __restrict__ b3,
    const float* __restrict__ w4, const float* __restrict__ b4,
    float* __restrict__ out, int* __restrict__ flags,
    float* __restrict__ partials)
{
    const int tid = threadIdx.x;
    const int b   = blockIdx.x;

    unsigned long long* pub = (unsigned long long*)partials;

    __shared__ __align__(16) float lw3[4 * 2048];    // 32 KB row slice
    __shared__ __align__(16) float lfeat[2048];
    __shared__ __align__(16) float lc2[512], lc3[512]; // next-step common conv feats
    __shared__ float lbase2[128], lbase3[128], ls5[128];
    __shared__ float ls0[6 * 128];                   // 6 s0 variants (constant)
    __shared__ float ltmp[512];                      // s1c (128) + s4c (384), constant
    __shared__ __align__(16) float lcw[512];
    __shared__ float lcb[128];
    __shared__ float lw0v[128], lb0v[128], lw1v[128], lb1v[128];
    __shared__ float lw2v[128], lb2v[128], lb3v[128];
    __shared__ float lw4[768], lb4v[8];
    __shared__ float st2[8], st3[8], st4[8];
    __shared__ float sx[8];     // 0:st[0,7] 1:st[1,7] 2:st[4,7] 3:st[4,0] 4:vs
    __shared__ float lbw[8];
    __shared__ float h_lds[4], hv_lds[4 * 8];
    __shared__ float red[48];
    __shared__ float sval[32 * 48];                  // staged remote partials (g<2)
    __shared__ float hscr[4 * 2368];                 // 36 h-partials/lane, stride 37
    __shared__ float h36_lds[144];                   // reduced h per (wave,combo)
    __shared__ float sfan[258 * 32];                 // block-0 round-3 staging
    __shared__ int   sact[2];

    // ---- one-time staging ----
    {
        const float4* g4 = (const float4*)(w3 + b * 4 * 2048);
        float4* l4 = (float4*)lw3;
        for (int idx = tid; idx < 2048; idx += TPB) l4[idx] = g4[idx];
    }
    for (int idx = tid; idx < 512; idx += TPB) lcw[idx] = conv_w[idx];
    if (tid < 128) {
        lcb[tid]  = conv_b[tid];
        lw0v[tid] = w0[tid]; lb0v[tid] = b0[tid];
        lw1v[tid] = w1[tid]; lb1v[tid] = b1[tid];
        lw2v[tid] = w2[tid]; lb2v[tid] = b2[tid];
        lb3v[tid] = b3[tid];
    }
    for (int idx = tid; idx < 768; idx += TPB) lw4[idx] = w4[idx];
    if (tid < 6) lb4v[tid] = b4[tid];
    if (tid < 8) {
        st2[tid] = inp[16 + tid];
        st3[tid] = inp[24 + tid];
        st4[tid] = inp[32 + tid];
        lbw[tid] = inp[48 + tid];
    }
    if (tid == 0) {
        sx[0] = inp[7];   sx[1] = inp[15];
        sx[2] = inp[39];  sx[3] = inp[32];
        sx[4] = inp[56];
    }
    __syncthreads();

    // ---- constant-across-steps speculative feats ----
    if (tid < 128) {
        const float vb[6] = {300.f, 750.f, 1200.f, 1850.f, 2850.f, 4300.f};
        #pragma unroll
        for (int v = 0; v < 6; ++v)
            ls0[v * 128 + tid] = relu_(vb[v] * (1.f / 4300.f) * lw0v[tid] + lb0v[tid]);
        ltmp[tid] = relu_(3.0f * lw1v[tid] + lb1v[tid]);       // s1 after any update
    }
    for (int m = tid; m < 384; m += TPB) {                     // s4 after any update
        int c = m / 3, w = m - c * 3;
        float a = lcb[c];
        #pragma unroll
        for (int k = 0; k < 4; ++k)
            a += sx[4] * (float)(1 << (w + k)) * 1e-6f * lcw[c * 4 + k];
        ltmp[128 + m] = relu_(a);
    }
    __syncthreads();

    const int wv = tid >> 6, lane = tid & 63;
    const float* wr = lw3 + wv * 2048;                          // this wave's w3 row
    const float bias3 = lb3v[b * 4 + wv];

    // per-lane constant dot-partials: hs0p[v] (s0 variants), hs14p (s1+s4)
    float hs0p[6], hs14p;
    #pragma unroll
    for (int v = 0; v < 6; ++v)
        hs0p[v] = wr[lane] * ls0[v * 128 + lane] + wr[64 + lane] * ls0[v * 128 + 64 + lane];
    hs14p = wr[128 + lane] * ltmp[lane] + wr[192 + lane] * ltmp[64 + lane];
    #pragma unroll
    for (int k = 0; k < 6; ++k) {
        int m = lane + 64 * k;
        hs14p += wr[1536 + m] * ltmp[128 + m];
    }

    const float VBRc[6] = {300.f, 750.f, 1200.f, 1850.f, 2850.f, 4300.f};

    // poll-task list for rounds 0,1: 1344 tasks over 256 threads
    int tb[6], te[6], myN = 0;
    #pragma unroll
    for (int r = 0; r < 6; ++r) {
        int idx = tid + 256 * r;
        if (idx < 1344) { tb[myN] = idx / 42; te[myN] = idx - 42 * (idx / 42); ++myN; }
    }

    for (int g = 0; g < 3; ++g) {
        const int i = 2 * g;

        // ---- Phase A: feat_i (exact) + next-step common pieces ----
        if (tid < 128) {
            lfeat[tid]        = relu_(sx[0] * lw0v[tid] + lb0v[tid]);   // s0
            lfeat[1920 + tid] =        sx[2] * lw2v[tid] + lb2v[tid];   // s5 (no relu)
            lbase2[tid] = st2[5] * lcw[tid*4] + st2[6] * lcw[tid*4+1]
                        + st2[7] * lcw[tid*4+2] + lcb[tid];
            lbase3[tid] = st3[5] * lcw[tid*4] + st3[6] * lcw[tid*4+1]
                        + st3[7] * lcw[tid*4+2] + lcb[tid];
            ls5[tid] = sx[3] * lw2v[tid] + lb2v[tid];                   // next s5
        } else {
            int j = tid - 128;
            lfeat[128 + j] = relu_(sx[1] * lw1v[j] + lb1v[j]);          // s1
        }
        for (int m = tid; m < 640; m += TPB) {                          // s2, s3
            int c = m / 5, w = m - c * 5;
            float a2 = lcb[c], a3 = lcb[c];
            #pragma unroll
            for (int k = 0; k < 4; ++k) {
                float cw = lcw[c * 4 + k];
                a2 += st2[w + k] * cw;
                a3 += st3[w + k] * cw;
            }
            lfeat[256 + m] = relu_(a2);
            lfeat[896 + m] = relu_(a3);
        }
        for (int m = tid; m < 384; m += TPB) {                          // s4
            int c = m / 3, w = m - c * 3;
            float a4 = lcb[c];
            #pragma unroll
            for (int k = 0; k < 4; ++k) a4 += st4[w + k] * lcw[c * 4 + k];
            lfeat[1536 + m] = relu_(a4);
        }
        for (int m = tid; m < 512; m += TPB) {       // next-step s2/s3 windows 0..3
            int c = m >> 2, w = m & 3;
            float a2 = lcb[c], a3 = lcb[c];
            #pragma unroll
            for (int k = 0; k < 4; ++k) {
                float cw = lcw[c * 4 + k];
                a2 += st2[w + 1 + k] * cw;
                a3 += st3[w + 1 + k] * cw;
            }
            lc2[m] = relu_(a2);
            lc3[m] = relu_(a3);
        }
        __syncthreads();

        // ---- Phase B: wave dots ----
        float acc_i;
        {
            const float4* w4p = (const float4*)wr;
            const float4* f4p = (const float4*)lfeat;
            float4 acc = make_float4(0.f, 0.f, 0.f, 0.f);
            #pragma unroll
            for (int it = 0; it < 8; ++it) {
                float4 a = w4p[it * 64 + lane];
                float4 f = f4p[it * 64 + lane];
                acc.x += a.x * f.x; acc.y += a.y * f.y;
                acc.z += a.z * f.z; acc.w += a.w * f.w;
            }
            acc_i = (acc.x + acc.y) + (acc.z + acc.w);
        }

        float s5c = wr[1920 + lane] * ls5[lane] + wr[1984 + lane] * ls5[64 + lane];
        float acc_c = hs14p + s5c;
        #pragma unroll
        for (int k = 0; k < 8; ++k) {
            int m = lane + 64 * k;
            int col = 256 + (m >> 2) * 5 + (m & 3);
            acc_c += wr[col] * lc2[m] + wr[640 + col] * lc3[m];
        }

        float n2[6], n3[6];
        {
            float bwi = lbw[i], vs = sx[4];
            #pragma unroll
            for (int v = 0; v < 6; ++v) {
                float vca   = vs * (float)(1 << v);
                float delay = vca / bwi - 30000.f;
                n2[v] = vca / delay * 1e-3f;
                n3[v] = delay * 1e-4f;
            }
        }
        float accv[6];
        #pragma unroll
        for (int v = 0; v < 6; ++v) accv[v] = hs0p[v];
        #pragma unroll
        for (int t = 0; t < 2; ++t) {
            int c = lane + 64 * t;
            float cw3 = lcw[c * 4 + 3];
            float bb2 = lbase2[c], bb3 = lbase3[c];
            float wc2 = wr[256 + c * 5 + 4], wc3 = wr[896 + c * 5 + 4];
            #pragma unroll
            for (int v = 0; v < 6; ++v)
                accv[v] += relu_(bb2 + n2[v] * cw3) * wc2
                         + relu_(bb3 + n3[v] * cw3) * wc3;
        }

        // ---- g==2: compute all 36 final-combo per-lane h partials ----
        if (g == 2) {
            float fcom_f = hs14p + s5c;     // s1 + s4 + s5 of final state
            float lb2s[2], lb3s[2], b4f2[2], b4f3[2];
            float cw2s[2], cw3s[2], w32s[2], w33s[2], w42s[2], w43s[2];
            #pragma unroll
            for (int t = 0; t < 2; ++t) {
                int c = lane + 64 * t;
                float c0 = lcw[c*4], c1 = lcw[c*4+1], c2 = lcw[c*4+2], c3 = lcw[c*4+3];
                cw2s[t] = c2; cw3s[t] = c3;
                lb2s[t] = lbase2[c];  lb3s[t] = lbase3[c];   // final win3 base
                b4f2[t] = st2[6]*c0 + st2[7]*c1 + lcb[c];    // final win4 base (s2)
                b4f3[t] = st3[6]*c0 + st3[7]*c1 + lcb[c];    // final win4 base (s3)
                w32s[t] = wr[256 + c*5 + 3]; w33s[t] = wr[896 + c*5 + 3];
                w42s[t] = wr[256 + c*5 + 4]; w43s[t] = wr[896 + c*5 + 4];
                #pragma unroll
                for (int w = 0; w < 3; ++w) {                // final win0..2 (known now)
                    float a2 = st2[2+w]*c0 + st2[3+w]*c1 + st2[4+w]*c2 + st2[5+w]*c3 + lcb[c];
                    float a3 = st3[2+w]*c0 + st3[3+w]*c1 + st3[4+w]*c2 + st3[5+w]*c3 + lcb[c];
                    fcom_f += relu_(a2) * wr[256 + c*5 + w] + relu_(a3) * wr[896 + c*5 + w];
                }
            }
            // step-5 row updates under action v with bw[5] (== old ap25/ap35)
            float ap5[6], ap35[6];
            {
                float bw5 = lbw[5], vs = sx[4];
                #pragma unroll
                for (int v = 0; v < 6; ++v) {
                    float vca = vs * (float)(1 << v);
                    float d   = vca / bw5 - 30000.f;
                    ap5[v]  = vca / d * 1e-3f;
                    ap35[v] = d * 1e-4f;
                }
            }
            // n2[u]/n3[u] here use bw[4] (i==4) == old ap24/ap34 bit-exactly.
            const int sbase = wv * 2368 + lane * 37;
            #pragma unroll
            for (int u = 0; u < 6; ++u) {
                float r32[2], r33[2];
                #pragma unroll
                for (int t = 0; t < 2; ++t) {
                    r32[t] = relu_(lb2s[t] + n2[u] * cw3s[t]);
                    r33[t] = relu_(lb3s[t] + n3[u] * cw3s[t]);
                }
                #pragma unroll
                for (int v = 0; v < 6; ++v) {
                    float hl = fcom_f + hs0p[v];
                    #pragma unroll
                    for (int t = 0; t < 2; ++t) {
                        float r42 = relu_(b4f2[t] + n2[u] * cw2s[t] + ap5[v]  * cw3s[t]);
                        float r43 = relu_(b4f3[t] + n3[u] * cw2s[t] + ap35[v] * cw3s[t]);
                        hl += r32[t] * w32s[t] + r33[t] * w33s[t]
                            + r42 * w42s[t] + r43 * w43s[t];
                    }
                    hscr[sbase + u * 6 + v] = hl;
                }
            }
        }

        #pragma unroll
        for (int off = 32; off > 0; off >>= 1) {
            acc_i += __shfl_xor(acc_i, off);
            acc_c += __shfl_xor(acc_c, off);
            #pragma unroll
            for (int v = 0; v < 6; ++v) accv[v] += __shfl_xor(accv[v], off);
        }
        if (lane == 0) {
            h_lds[wv] = relu_(acc_i + bias3);
            #pragma unroll
            for (int v = 0; v < 6; ++v)
                hv_lds[wv * 8 + v] = relu_(acc_c + accv[v] + bias3);
        }
        __syncthreads();

        if (g < 2) {
            // ---- Phase C': publish 42 fused {data,seq} u64s ----
            if (tid < 42) {
                int q = tid / 6, t = tid - q * 6;
                float p = 0.f;
                if (q == 0) {
                    #pragma unroll
                    for (int w = 0; w < 4; ++w) p += lw4[t * 128 + b * 4 + w] * h_lds[w];
                } else {
                    #pragma unroll
                    for (int w = 0; w < 4; ++w) p += lw4[t * 128 + b * 4 + w] * hv_lds[w * 8 + (q - 1)];
                }
                union { float f[2]; unsigned long long u; } x;
                x.f[0] = p; x.f[1] = (float)(g + 1);
                __hip_atomic_store(&pub[(g * NBLK + b) * PSTRIDE64 + tid], x.u,
                                   __ATOMIC_RELAXED, __HIP_MEMORY_SCOPE_AGENT);
            }

            // ---- Phase D': parallel poll sweep ----
            {
                const unsigned int seqbits = __float_as_uint((float)(g + 1));
                unsigned int pend = (1u << myN) - 1u;
                while (pend) {
                    unsigned long long v[6];
                    #pragma unroll
                    for (int k = 0; k < 6; ++k) {
                        if (k < myN && (pend & (1u << k)))
                            v[k] = __hip_atomic_load(
                                &pub[(g * NBLK + tb[k]) * PSTRIDE64 + te[k]],
                                __ATOMIC_RELAXED, __HIP_MEMORY_SCOPE_AGENT);
                    }
                    #pragma unroll
                    for (int k = 0; k < 6; ++k) {
                        if (k < myN && (pend & (1u << k))) {
                            if ((unsigned int)(v[k] >> 32) == seqbits) {
                                sval[tb[k] * 48 + te[k]] =
                                    __uint_as_float((unsigned int)(v[k] & 0xFFFFFFFFu));
                                pend &= ~(1u << k);
                            }
                        }
                    }
                    if (pend) __builtin_amdgcn_s_sleep(1);
                }
            }
            __syncthreads();

            // deterministic fan-in, bb=0..31 order
            if (tid < 42) {
                float p = lb4v[tid % 6];
                #pragma unroll
                for (int bb = 0; bb < NBLK; ++bb) p += sval[bb * 48 + tid];
                red[tid] = p;
            }
            __syncthreads();
            if (tid == 0) {
                float best = red[0]; int a0 = 0;
                #pragma unroll
                for (int r = 1; r < 6; ++r) if (red[r] > best) { best = red[r]; a0 = r; }
                best = red[6 + 6 * a0]; int a1 = 0;
                #pragma unroll
                for (int r = 1; r < 6; ++r)
                    if (red[6 + 6 * a0 + r] > best) { best = red[6 + 6 * a0 + r]; a1 = r; }

                // update(i, a0)
                {
                    float vca = sx[4] * (float)(1 << a0);
                    float delay = vca / lbw[i] - 30000.f;
                    sx[0] = VBRc[a0] * (1.f / 4300.f);
                    sx[1] = 3.0f;
                    #pragma unroll
                    for (int c = 0; c < 7; ++c) { st2[c] = st2[c + 1]; st3[c] = st3[c + 1]; }
                    st2[7] = vca / delay * 1e-3f;
                    st3[7] = delay * 1e-4f;
                    sx[2] = sx[3]; sx[3] = sx[4] * 1e-6f;
                    #pragma unroll
                    for (int j = 0; j < 6; ++j) st4[j] = sx[4] * (float)(1 << j) * 1e-6f;
                }
                // update(i+1, a1)
                {
                    float vca = sx[4] * (float)(1 << a1);
                    float delay = vca / lbw[i + 1] - 30000.f;
                    sx[0] = VBRc[a1] * (1.f / 4300.f);
                    sx[1] = 3.0f;
                    #pragma unroll
                    for (int c = 0; c < 7; ++c) { st2[c] = st2[c + 1]; st3[c] = st3[c + 1]; }
                    st2[7] = vca / delay * 1e-3f;
                    st3[7] = delay * 1e-4f;
                    sx[2] = sx[3]; sx[3] = sx[4] * 1e-6f;
                    #pragma unroll
                    for (int j = 0; j < 6; ++j) st4[j] = sx[4] * (float)(1 << j) * 1e-6f;
                }
            }
            __syncthreads();
        } else {
            // ---- round 3: reduce h36 columns in butterfly-tree order ----
            // (hscr complete for all waves since the __syncthreads above)
            if (tid < 144) {
                const int wvr = tid / 36, m = tid - 36 * wvr;
                const int base = wvr * 2368 + m;
                float a[64];
                #pragma unroll
                for (int l = 0; l < 64; ++l) a[l] = hscr[base + l * 37];
                #pragma unroll
                for (int off = 32; off > 0; off >>= 1)
                    #pragma unroll
                    for (int ii = 0; ii < 32; ++ii)
                        if (ii < off) a[ii] += a[ii + off];
                h36_lds[wvr * 36 + m] = relu_(a[0] + lb3v[b * 4 + wvr]);
            }
            __syncthreads();

            // ---- publish 258 fused u64s (42 group + 216 final-combo) ----
            for (int e = tid; e < 258; e += TPB) {
                float p = 0.f;
                if (e < 42) {
                    int q = e / 6, t = e - q * 6;
                    if (q == 0) {
                        #pragma unroll
                        for (int w = 0; w < 4; ++w) p += lw4[t * 128 + b * 4 + w] * h_lds[w];
                    } else {
                        #pragma unroll
                        for (int w = 0; w < 4; ++w) p += lw4[t * 128 + b * 4 + w] * hv_lds[w * 8 + (q - 1)];
                    }
                } else {
                    int c = (e - 42) / 6, t = (e - 42) - 6 * ((e - 42) / 6);
                    #pragma unroll
                    for (int w = 0; w < 4; ++w) p += lw4[t * 128 + b * 4 + w] * h36_lds[w * 36 + c];
                }
                union { float f[2]; unsigned long long u; } x;
                x.f[0] = p; x.f[1] = 3.0f;
                __hip_atomic_store(&pub[R3BASE + b * R3STRIDE + e], x.u,
                                   __ATOMIC_RELAXED, __HIP_MEMORY_SCOPE_AGENT);
            }

            // blocks 1..31 are done; only block 0 resolves + writes out
            if (b == 0) {
                const unsigned int seqbits = __float_as_uint(3.0f);
                // 8256 tasks over 256 threads: idx = tid + 256*r (r<32),
                // plus idx = 8192+tid for tid<64 (r==32)
                const int nt = (tid < 64) ? 33 : 32;
                unsigned long long pend = (nt == 33) ? ((1ull << 33) - 1ull)
                                                     : ((1ull << 32) - 1ull);
                while (pend) {
                    unsigned long long v[33];
                    #pragma unroll
                    for (int r = 0; r < 33; ++r) {
                        if (r < nt && (pend & (1ull << r))) {
                            int idx = (r < 32) ? (tid + 256 * r) : (8192 + tid);
                            int bb = idx / 258, e = idx - 258 * bb;
                            v[r] = __hip_atomic_load(&pub[R3BASE + bb * R3STRIDE + e],
                                                     __ATOMIC_RELAXED,
                                                     __HIP_MEMORY_SCOPE_AGENT);
                        }
                    }
                    #pragma unroll
                    for (int r = 0; r < 33; ++r) {
                        if (r < nt && (pend & (1ull << r))) {
                            if ((unsigned int)(v[r] >> 32) == seqbits) {
                                int idx = (r < 32) ? (tid + 256 * r) : (8192 + tid);
                                int bb = idx / 258, e = idx - 258 * bb;
                                sfan[e * 32 + bb] =
                                    __uint_as_float((unsigned int)(v[r] & 0xFFFFFFFFu));
                                pend &= ~(1ull << r);
                            }
                        }
                    }
                    if (pend) __builtin_amdgcn_s_sleep(1);
                }
                __syncthreads();

                if (tid < 42) {
                    float p = lb4v[tid % 6];
                    #pragma unroll
                    for (int bb = 0; bb < NBLK; ++bb) p += sfan[tid * 32 + bb];
                    red[tid] = p;
                }
                __syncthreads();
                if (tid == 0) {
                    float best = red[0]; int a0 = 0;
                    #pragma unroll
                    for (int r = 1; r < 6; ++r) if (red[r] > best) { best = red[r]; a0 = r; }
                    best = red[6 + 6 * a0]; int a1 = 0;
                    #pragma unroll
                    for (int r = 1; r < 6; ++r)
                        if (red[6 + 6 * a0 + r] > best) { best = red[6 + 6 * a0 + r]; a1 = r; }
                    sact[0] = a0; sact[1] = a1;
                }
                __syncthreads();
                if (tid < 6) {
                    float p = lb4v[tid];
                    const int e = 42 + (sact[0] * 6 + sact[1]) * 6 + tid;
                    #pragma unroll
                    for (int bb = 0; bb < NBLK; ++bb) p += sfan[e * 32 + bb];
                    out[tid] = p;
                }
            }
        }
    }
}

extern "C" void kernel_launch(void* const* d_in, const int* in_sizes, int n_in,
                              void* d_out, int out_size, void* d_ws, size_t ws_size,
                              hipStream_t stream) {
    const float* inp    = (const float*)d_in[0];
    const float* conv_w = (const float*)d_in[1];
    const float* conv_b = (const float*)d_in[2];
    const float* w0     = (const float*)d_in[3];
    const float* b0     = (const float*)d_in[4];
    const float* w1     = (const float*)d_in[5];
    const float* b1     = (const float*)d_in[6];
    const float* w2     = (const float*)d_in[7];
    const float* b2     = (const float*)d_in[8];
    const float* w3     = (const float*)d_in[9];
    const float* b3     = (const float*)d_in[10];
    const float* w4     = (const float*)d_in[11];
    const float* b4     = (const float*)d_in[12];

    int*   flags    = (int*)d_ws;                       // unused (kept for ABI)
    float* partials = (float*)((char*)d_ws + 8192);     // u64 region: see R3BASE

    actor_kernel<<<NBLK, TPB, 0, stream>>>(inp, conv_w, conv_b,
                                           w0, b0, w1, b1, w2, b2,
                                           w3, b3, w4, b4,
                                           (float*)d_out, flags, partials);
}

// Round 8
// 98.931 us; speedup vs baseline: 1.0658x; 1.0658x over previous
//
#include <hip/hip_runtime.h>

#define NBLK 32
#define TPB  256
#define PSTRIDE64 64   // publish slot stride in u64s (512 B per block-slot)

__device__ __forceinline__ float relu_(float x) { return fmaxf(x, 0.f); }

// R11 = exact revert to R7 champion (98.97 us): R3 4-round structure with the
// flag+gather protocol replaced by fused 8-byte {data,seq} atomics:
//   publisher: 42 relaxed agent u64 stores (data + float(g+1) packed) — no
//   vmcnt drain, no release, no flag.
//   readers: 1344 poll tasks over 256 threads, batched relaxed u64 loads
//   (validity+payload in the same load -> ONE cross-XCD RTT instead of
//   flag-RTT + data-RTT), staged to LDS, then summed in R3's exact
//   deterministic bb=0..31 order.
// Poison 0xAAAAAAAA in the seq word never equals float(1..4) -> no init
// kernel needed; slots are per-(round,block) so no ABA.
// Post-R7 ledger (all reverted): R8 T14 staging +0.9; R9 rolled g-loop +2.2;
// R10 4th-round fold +6.5 (R4 variant +7.1). Round-count, barrier-count,
// fan-in shape, staging overlap, and I$ footprint are all falsified levers.

__launch_bounds__(TPB, 1)
__global__ void actor_kernel(
    const float* __restrict__ inp,
    const float* __restrict__ conv_w, const float* __restrict__ conv_b,
    const float* __restrict__ w0, const float* __restrict__ b0,
    const float* __restrict__ w1, const float* __restrict__ b1,
    const float* __restrict__ w2, const float* __restrict__ b2,
    const float* __restrict__ w3, const float* __restrict__ b3,
    const float* __restrict__ w4, const float* __restrict__ b4,
    float* __restrict__ out, int* __restrict__ flags,
    float* __restrict__ partials)
{
    const int tid = threadIdx.x;
    const int b   = blockIdx.x;

    unsigned long long* pub = (unsigned long long*)partials;

    __shared__ __align__(16) float lw3[4 * 2048];    // 32 KB row slice
    __shared__ __align__(16) float lfeat[2048];
    __shared__ __align__(16) float lc2[512], lc3[512]; // next-step common conv feats
    __shared__ float lbase2[128], lbase3[128], ls5[128];
    __shared__ float ls0[6 * 128];                   // 6 s0 variants (constant)
    __shared__ float ltmp[512];                      // s1c (128) + s4c (384), constant
    __shared__ __align__(16) float lcw[512];
    __shared__ float lcb[128];
    __shared__ float lw0v[128], lb0v[128], lw1v[128], lb1v[128];
    __shared__ float lw2v[128], lb2v[128], lb3v[128];
    __shared__ float lw4[768], lb4v[8];
    __shared__ float st2[8], st3[8], st4[8];
    __shared__ float sx[8];     // 0:st[0,7] 1:st[1,7] 2:st[4,7] 3:st[4,0] 4:vs
    __shared__ float lbw[8];
    __shared__ float h_lds[4], hv_lds[4 * 8];
    __shared__ float red[48];
    __shared__ float sval[32 * 48];                  // staged remote partials
    __shared__ int   sact[2];

    // ---- one-time staging ----
    {
        const float4* g4 = (const float4*)(w3 + b * 4 * 2048);
        float4* l4 = (float4*)lw3;
        for (int idx = tid; idx < 2048; idx += TPB) l4[idx] = g4[idx];
    }
    for (int idx = tid; idx < 512; idx += TPB) lcw[idx] = conv_w[idx];
    if (tid < 128) {
        lcb[tid]  = conv_b[tid];
        lw0v[tid] = w0[tid]; lb0v[tid] = b0[tid];
        lw1v[tid] = w1[tid]; lb1v[tid] = b1[tid];
        lw2v[tid] = w2[tid]; lb2v[tid] = b2[tid];
        lb3v[tid] = b3[tid];
    }
    for (int idx = tid; idx < 768; idx += TPB) lw4[idx] = w4[idx];
    if (tid < 6) lb4v[tid] = b4[tid];
    if (tid < 8) {
        st2[tid] = inp[16 + tid];
        st3[tid] = inp[24 + tid];
        st4[tid] = inp[32 + tid];
        lbw[tid] = inp[48 + tid];
    }
    if (tid == 0) {
        sx[0] = inp[7];   sx[1] = inp[15];
        sx[2] = inp[39];  sx[3] = inp[32];
        sx[4] = inp[56];
    }
    __syncthreads();

    // ---- constant-across-steps speculative feats ----
    if (tid < 128) {
        const float vb[6] = {300.f, 750.f, 1200.f, 1850.f, 2850.f, 4300.f};
        #pragma unroll
        for (int v = 0; v < 6; ++v)
            ls0[v * 128 + tid] = relu_(vb[v] * (1.f / 4300.f) * lw0v[tid] + lb0v[tid]);
        ltmp[tid] = relu_(3.0f * lw1v[tid] + lb1v[tid]);       // s1 after any update
    }
    for (int m = tid; m < 384; m += TPB) {                     // s4 after any update
        int c = m / 3, w = m - c * 3;
        float a = lcb[c];
        #pragma unroll
        for (int k = 0; k < 4; ++k)
            a += sx[4] * (float)(1 << (w + k)) * 1e-6f * lcw[c * 4 + k];
        ltmp[128 + m] = relu_(a);
    }
    __syncthreads();

    const int wv = tid >> 6, lane = tid & 63;
    const float* wr = lw3 + wv * 2048;                          // this wave's w3 row
    const float bias3 = lb3v[b * 4 + wv];

    // per-lane constant dot-partials: hs0p[v] (s0 variants), hs14p (s1+s4)
    float hs0p[6], hs14p;
    #pragma unroll
    for (int v = 0; v < 6; ++v)
        hs0p[v] = wr[lane] * ls0[v * 128 + lane] + wr[64 + lane] * ls0[v * 128 + 64 + lane];
    hs14p = wr[128 + lane] * ltmp[lane] + wr[192 + lane] * ltmp[64 + lane];
    #pragma unroll
    for (int k = 0; k < 6; ++k) {
        int m = lane + 64 * k;
        hs14p += wr[1536 + m] * ltmp[128 + m];
    }

    const float VBRc[6] = {300.f, 750.f, 1200.f, 1850.f, 2850.f, 4300.f};

    // poll-task list: 1344 tasks = (bb 0..31) x (e 0..41), spread over 256 threads
    int tb[6], te[6], myN = 0;
    #pragma unroll
    for (int r = 0; r < 6; ++r) {
        int idx = tid + 256 * r;
        if (idx < 1344) { tb[myN] = idx / 42; te[myN] = idx - 42 * (idx / 42); ++myN; }
    }

    // final-phase captures (filled during g==2 Phase B)
    float fcom_f = 0.f;
    float lb2s[2], lb3s[2], b4f2[2], b4f3[2];
    float cw2s[2], cw3s[2], w32s[2], w33s[2], w42s[2], w43s[2];

    for (int g = 0; g < 3; ++g) {
        const int i = 2 * g;

        // ---- Phase A: feat_i (exact) + next-step common pieces ----
        if (tid < 128) {
            lfeat[tid]        = relu_(sx[0] * lw0v[tid] + lb0v[tid]);   // s0
            lfeat[1920 + tid] =        sx[2] * lw2v[tid] + lb2v[tid];   // s5 (no relu)
            lbase2[tid] = st2[5] * lcw[tid*4] + st2[6] * lcw[tid*4+1]
                        + st2[7] * lcw[tid*4+2] + lcb[tid];
            lbase3[tid] = st3[5] * lcw[tid*4] + st3[6] * lcw[tid*4+1]
                        + st3[7] * lcw[tid*4+2] + lcb[tid];
            ls5[tid] = sx[3] * lw2v[tid] + lb2v[tid];                   // next s5
        } else {
            int j = tid - 128;
            lfeat[128 + j] = relu_(sx[1] * lw1v[j] + lb1v[j]);          // s1
        }
        for (int m = tid; m < 640; m += TPB) {                          // s2, s3
            int c = m / 5, w = m - c * 5;
            float a2 = lcb[c], a3 = lcb[c];
            #pragma unroll
            for (int k = 0; k < 4; ++k) {
                float cw = lcw[c * 4 + k];
                a2 += st2[w + k] * cw;
                a3 += st3[w + k] * cw;
            }
            lfeat[256 + m] = relu_(a2);
            lfeat[896 + m] = relu_(a3);
        }
        for (int m = tid; m < 384; m += TPB) {                          // s4
            int c = m / 3, w = m - c * 3;
            float a4 = lcb[c];
            #pragma unroll
            for (int k = 0; k < 4; ++k) a4 += st4[w + k] * lcw[c * 4 + k];
            lfeat[1536 + m] = relu_(a4);
        }
        for (int m = tid; m < 512; m += TPB) {       // next-step s2/s3 windows 0..3
            int c = m >> 2, w = m & 3;
            float a2 = lcb[c], a3 = lcb[c];
            #pragma unroll
            for (int k = 0; k < 4; ++k) {
                float cw = lcw[c * 4 + k];
                a2 += st2[w + 1 + k] * cw;
                a3 += st3[w + 1 + k] * cw;
            }
            lc2[m] = relu_(a2);
            lc3[m] = relu_(a3);
        }
        __syncthreads();

        // ---- Phase B: wave dots ----
        float acc_i;
        {
            const float4* w4p = (const float4*)wr;
            const float4* f4p = (const float4*)lfeat;
            float4 acc = make_float4(0.f, 0.f, 0.f, 0.f);
            #pragma unroll
            for (int it = 0; it < 8; ++it) {
                float4 a = w4p[it * 64 + lane];
                float4 f = f4p[it * 64 + lane];
                acc.x += a.x * f.x; acc.y += a.y * f.y;
                acc.z += a.z * f.z; acc.w += a.w * f.w;
            }
            acc_i = (acc.x + acc.y) + (acc.z + acc.w);
        }

        float s5c = wr[1920 + lane] * ls5[lane] + wr[1984 + lane] * ls5[64 + lane];
        float acc_c = hs14p + s5c;
        #pragma unroll
        for (int k = 0; k < 8; ++k) {
            int m = lane + 64 * k;
            int col = 256 + (m >> 2) * 5 + (m & 3);
            acc_c += wr[col] * lc2[m] + wr[640 + col] * lc3[m];
        }

        float n2[6], n3[6];
        {
            float bwi = lbw[i], vs = sx[4];
            #pragma unroll
            for (int v = 0; v < 6; ++v) {
                float vca   = vs * (float)(1 << v);
                float delay = vca / bwi - 30000.f;
                n2[v] = vca / delay * 1e-3f;
                n3[v] = delay * 1e-4f;
            }
        }
        float accv[6];
        #pragma unroll
        for (int v = 0; v < 6; ++v) accv[v] = hs0p[v];
        #pragma unroll
        for (int t = 0; t < 2; ++t) {
            int c = lane + 64 * t;
            float cw3 = lcw[c * 4 + 3];
            float bb2 = lbase2[c], bb3 = lbase3[c];
            float wc2 = wr[256 + c * 5 + 4], wc3 = wr[896 + c * 5 + 4];
            #pragma unroll
            for (int v = 0; v < 6; ++v)
                accv[v] += relu_(bb2 + n2[v] * cw3) * wc2
                         + relu_(bb3 + n3[v] * cw3) * wc3;
        }

        // ---- g==2: capture final-eval pre-resolve parts (pure registers) ----
        if (g == 2) {
            fcom_f = hs14p + s5c;       // s1 + s4 + s5 of final state
            #pragma unroll
            for (int t = 0; t < 2; ++t) {
                int c = lane + 64 * t;
                float c0 = lcw[c*4], c1 = lcw[c*4+1], c2 = lcw[c*4+2], c3 = lcw[c*4+3];
                cw2s[t] = c2; cw3s[t] = c3;
                lb2s[t] = lbase2[c];  lb3s[t] = lbase3[c];   // final win3 base
                b4f2[t] = st2[6]*c0 + st2[7]*c1 + lcb[c];    // final win4 base (s2)
                b4f3[t] = st3[6]*c0 + st3[7]*c1 + lcb[c];    // final win4 base (s3)
                w32s[t] = wr[256 + c*5 + 3]; w33s[t] = wr[896 + c*5 + 3];
                w42s[t] = wr[256 + c*5 + 4]; w43s[t] = wr[896 + c*5 + 4];
                #pragma unroll
                for (int w = 0; w < 3; ++w) {                // final win0..2 (known now)
                    float a2 = st2[2+w]*c0 + st2[3+w]*c1 + st2[4+w]*c2 + st2[5+w]*c3 + lcb[c];
                    float a3 = st3[2+w]*c0 + st3[3+w]*c1 + st3[4+w]*c2 + st3[5+w]*c3 + lcb[c];
                    fcom_f += relu_(a2) * wr[256 + c*5 + w] + relu_(a3) * wr[896 + c*5 + w];
                }
            }
        }

        #pragma unroll
        for (int off = 32; off > 0; off >>= 1) {
            acc_i += __shfl_xor(acc_i, off);
            acc_c += __shfl_xor(acc_c, off);
            #pragma unroll
            for (int v = 0; v < 6; ++v) accv[v] += __shfl_xor(accv[v], off);
        }
        if (lane == 0) {
            h_lds[wv] = relu_(acc_i + bias3);
            #pragma unroll
            for (int v = 0; v < 6; ++v)
                hv_lds[wv * 8 + v] = relu_(acc_c + accv[v] + bias3);
        }
        __syncthreads();

        // ---- Phase C': publish 42 fused {data,seq} u64s (relaxed, no flag) ----
        if (tid < 42) {
            int q = tid / 6, t = tid - q * 6;
            float p = 0.f;
            if (q == 0) {
                #pragma unroll
                for (int w = 0; w < 4; ++w) p += lw4[t * 128 + b * 4 + w] * h_lds[w];
            } else {
                #pragma unroll
                for (int w = 0; w < 4; ++w) p += lw4[t * 128 + b * 4 + w] * hv_lds[w * 8 + (q - 1)];
            }
            union { float f[2]; unsigned long long u; } x;
            x.f[0] = p; x.f[1] = (float)(g + 1);
            __hip_atomic_store(&pub[(g * NBLK + b) * PSTRIDE64 + tid], x.u,
                               __ATOMIC_RELAXED, __HIP_MEMORY_SCOPE_AGENT);
        }

        // ---- Phase D': parallel poll sweep (validity+payload in one load) ----
        {
            const unsigned int seqbits = __float_as_uint((float)(g + 1));
            unsigned int pend = (1u << myN) - 1u;
            while (pend) {
                unsigned long long v[6];
                #pragma unroll
                for (int k = 0; k < 6; ++k) {
                    if (k < myN && (pend & (1u << k)))
                        v[k] = __hip_atomic_load(
                            &pub[(g * NBLK + tb[k]) * PSTRIDE64 + te[k]],
                            __ATOMIC_RELAXED, __HIP_MEMORY_SCOPE_AGENT);
                }
                #pragma unroll
                for (int k = 0; k < 6; ++k) {
                    if (k < myN && (pend & (1u << k))) {
                        if ((unsigned int)(v[k] >> 32) == seqbits) {
                            sval[tb[k] * 48 + te[k]] =
                                __uint_as_float((unsigned int)(v[k] & 0xFFFFFFFFu));
                            pend &= ~(1u << k);
                        }
                    }
                }
                if (pend) __builtin_amdgcn_s_sleep(1);
            }
        }
        __syncthreads();

        // deterministic fan-in, R3's exact bb=0..31 order
        if (tid < 42) {
            float p = lb4v[tid % 6];
            #pragma unroll
            for (int bb = 0; bb < NBLK; ++bb) p += sval[bb * 48 + tid];
            red[tid] = p;
        }
        __syncthreads();
        if (tid == 0) {
            float best = red[0]; int a0 = 0;
            #pragma unroll
            for (int r = 1; r < 6; ++r) if (red[r] > best) { best = red[r]; a0 = r; }
            best = red[6 + 6 * a0]; int a1 = 0;
            #pragma unroll
            for (int r = 1; r < 6; ++r)
                if (red[6 + 6 * a0 + r] > best) { best = red[6 + 6 * a0 + r]; a1 = r; }

            if (g == 2) {
                sact[0] = a0; sact[1] = a1;   // states no longer needed
            } else {
                // update(i, a0)
                {
                    float vca = sx[4] * (float)(1 << a0);
                    float delay = vca / lbw[i] - 30000.f;
                    sx[0] = VBRc[a0] * (1.f / 4300.f);
                    sx[1] = 3.0f;
                    #pragma unroll
                    for (int c = 0; c < 7; ++c) { st2[c] = st2[c + 1]; st3[c] = st3[c + 1]; }
                    st2[7] = vca / delay * 1e-3f;
                    st3[7] = delay * 1e-4f;
                    sx[2] = sx[3]; sx[3] = sx[4] * 1e-6f;
                    #pragma unroll
                    for (int j = 0; j < 6; ++j) st4[j] = sx[4] * (float)(1 << j) * 1e-6f;
                }
                // update(i+1, a1)
                {
                    float vca = sx[4] * (float)(1 << a1);
                    float delay = vca / lbw[i + 1] - 30000.f;
                    sx[0] = VBRc[a1] * (1.f / 4300.f);
                    sx[1] = 3.0f;
                    #pragma unroll
                    for (int c = 0; c < 7; ++c) { st2[c] = st2[c + 1]; st3[c] = st3[c + 1]; }
                    st2[7] = vca / delay * 1e-3f;
                    st3[7] = delay * 1e-4f;
                    sx[2] = sx[3]; sx[3] = sx[4] * 1e-6f;
                    #pragma unroll
                    for (int j = 0; j < 6; ++j) st4[j] = sx[4] * (float)(1 << j) * 1e-6f;
                }
            }
        }
        __syncthreads();
    }

    // ---- final eval: ~50 ops from captured registers, one shfl chain ----
    {
        const int a4 = sact[0], a5 = sact[1];
        float vs = sx[4];
        float vca4 = vs * (float)(1 << a4);
        float d4   = vca4 / lbw[4] - 30000.f;
        float ap24 = vca4 / d4 * 1e-3f, ap34 = d4 * 1e-4f;
        float vca5 = vs * (float)(1 << a5);
        float d5   = vca5 / lbw[5] - 30000.f;
        float ap25 = vca5 / d5 * 1e-3f, ap35 = d5 * 1e-4f;

        float h0 = hs0p[0];
        h0 = (a5 == 1) ? hs0p[1] : h0;
        h0 = (a5 == 2) ? hs0p[2] : h0;
        h0 = (a5 == 3) ? hs0p[3] : h0;
        h0 = (a5 == 4) ? hs0p[4] : h0;
        h0 = (a5 == 5) ? hs0p[5] : h0;

        float hl = fcom_f + h0;
        #pragma unroll
        for (int t = 0; t < 2; ++t) {
            float r32 = relu_(lb2s[t] + ap24 * cw3s[t]);                       // final win3 s2
            float r33 = relu_(lb3s[t] + ap34 * cw3s[t]);                       // final win3 s3
            float r42 = relu_(b4f2[t] + ap24 * cw2s[t] + ap25 * cw3s[t]);      // final win4 s2
            float r43 = relu_(b4f3[t] + ap34 * cw2s[t] + ap35 * cw3s[t]);      // final win4 s3
            hl += r32 * w32s[t] + r33 * w33s[t] + r42 * w42s[t] + r43 * w43s[t];
        }
        #pragma unroll
        for (int off = 32; off > 0; off >>= 1) hl += __shfl_xor(hl, off);
        if (lane == 0) h_lds[wv] = relu_(hl + bias3);
    }
    __syncthreads();

    // ---- final light round: fused u64 publish; block 0 polls + writes out ----
    if (tid < 6) {
        float p = 0.f;
        #pragma unroll
        for (int w = 0; w < 4; ++w) p += lw4[tid * 128 + b * 4 + w] * h_lds[w];
        union { float f[2]; unsigned long long u; } x;
        x.f[0] = p; x.f[1] = 4.0f;
        __hip_atomic_store(&pub[(3 * NBLK + b) * PSTRIDE64 + tid], x.u,
                           __ATOMIC_RELAXED, __HIP_MEMORY_SCOPE_AGENT);
    }
    if (b == 0) {
        if (tid < 192) {
            int bb = tid / 6, e = tid - 6 * bb;
            const unsigned int seqbits = __float_as_uint(4.0f);
            for (;;) {
                unsigned long long u = __hip_atomic_load(
                    &pub[(3 * NBLK + bb) * PSTRIDE64 + e],
                    __ATOMIC_RELAXED, __HIP_MEMORY_SCOPE_AGENT);
                if ((unsigned int)(u >> 32) == seqbits) {
                    sval[bb * 48 + e] =
                        __uint_as_float((unsigned int)(u & 0xFFFFFFFFu));
                    break;
                }
                __builtin_amdgcn_s_sleep(1);
            }
        }
        __syncthreads();
        if (tid < 6) {
            float p = lb4v[tid];
            #pragma unroll
            for (int bb = 0; bb < NBLK; ++bb) p += sval[bb * 48 + tid];
            out[tid] = p;
        }
    }
}

extern "C" void kernel_launch(void* const* d_in, const int* in_sizes, int n_in,
                              void* d_out, int out_size, void* d_ws, size_t ws_size,
                              hipStream_t stream) {
    const float* inp    = (const float*)d_in[0];
    const float* conv_w = (const float*)d_in[1];
    const float* conv_b = (const float*)d_in[2];
    const float* w0     = (const float*)d_in[3];
    const float* b0     = (const float*)d_in[4];
    const float* w1     = (const float*)d_in[5];
    const float* b1     = (const float*)d_in[6];
    const float* w2     = (const float*)d_in[7];
    const float* b2     = (const float*)d_in[8];
    const float* w3     = (const float*)d_in[9];
    const float* b3     = (const float*)d_in[10];
    const float* w4     = (const float*)d_in[11];
    const float* b4     = (const float*)d_in[12];

    int*   flags    = (int*)d_ws;                       // unused (kept for ABI)
    float* partials = (float*)((char*)d_ws + 8192);     // 4*32 slots * 512 B (u64)

    actor_kernel<<<NBLK, TPB, 0, stream>>>(inp, conv_w, conv_b,
                                           w0, b0, w1, b1, w2, b2,
                                           w3, b3, w4, b4,
                                           (float*)d_out, flags, partials);
}